// Round 8
// baseline (608.649 us; speedup 1.0000x reference)
//
#include <hip/hip_runtime.h>

typedef unsigned short u16;
typedef __attribute__((ext_vector_type(8))) __bf16 bf16x8;
typedef __attribute__((ext_vector_type(4))) __bf16 bf16x4;
typedef __attribute__((ext_vector_type(8))) unsigned short u16x8;
typedef __attribute__((ext_vector_type(4))) unsigned short u16x4;
typedef __attribute__((ext_vector_type(4))) float f32x4;

#define AS1 __attribute__((address_space(1)))
#define AS3 __attribute__((address_space(3)))

__device__ __forceinline__ void load_lds16(const void* g, void* l) {
  __builtin_amdgcn_global_load_lds((const AS1 unsigned int*)g,
                                   (AS3 unsigned int*)l, 16, 0, 0);
}

__device__ __forceinline__ float bf2f(u16 u) {
  unsigned int x = ((unsigned int)u) << 16;
  return __builtin_bit_cast(float, x);
}
__device__ __forceinline__ u16 f2bf(float f) {
  unsigned int x = __builtin_bit_cast(unsigned int, f);
  x += 0x7fffu + ((x >> 16) & 1u);
  return (u16)(x >> 16);
}
// load 8 consecutive f32, RNE-convert to bf16x8
__device__ __forceinline__ bf16x8 cvt8(const float* p) {
  f32x4 a = *(const f32x4*)p;
  f32x4 b = *(const f32x4*)(p + 4);
  u16x8 r;
#pragma unroll
  for (int j = 0; j < 4; ++j) { r[j] = f2bf(a[j]); r[4 + j] = f2bf(b[j]); }
  return __builtin_bit_cast(bf16x8, r);
}

// ---------------------------------------------------------------- f32 -> bf16 bulk convert
__global__ __launch_bounds__(256) void cvt_bf16_kernel(const float* __restrict__ in,
                                                       u16* __restrict__ out) {
  const int i = (blockIdx.x * 256 + threadIdx.x) * 8;
  *(bf16x8*)&out[i] = cvt8(in + i);
}

// ---------------------------------------------------------------- weight transpose (v1, verified)
// out[c - col0][r] = bf16(in[r*C + c])  for c in [col0, col0+Cpanel)
// 32x33-padded LDS tile: conflict-free.
__global__ __launch_bounds__(256) void transpose_w(const float* __restrict__ in,
                                                   u16* __restrict__ out,
                                                   int R, int C, int col0) {
  __shared__ u16 tile[32][33];
  const int tx = threadIdx.x & 31, ty = threadIdx.x >> 5;
  const int c0 = blockIdx.x * 32, r0 = blockIdx.y * 32;  // c0: panel-local col
#pragma unroll
  for (int j = ty; j < 32; j += 8)
    tile[j][tx] = f2bf(in[(size_t)(r0 + j) * C + col0 + c0 + tx]);
  __syncthreads();
#pragma unroll
  for (int j = ty; j < 32; j += 8)
    out[(size_t)(c0 + j) * R + r0 + tx] = tile[tx][j];
}

// ---------------------------------------------------------------- GEMM (deep pipeline, T4)
// C[M,N] = A[M,K] @ Bt[N,K]^T, A,Bt bf16.  BM=128, BN=256, BK=64, 512 thr =
// 8 waves (2M x 4N, wave owns 64x64).  Triple-buffered LDS (144 KiB).
// Counted-vmcnt discipline (T4): per K-tile [s_waitcnt vmcnt(6); s_barrier;
// stage(kt+2); ds_read; MFMA].  For kt <= NT-2 the wave has stage(kt) (6) +
// stage(kt+1) (6) outstanding, so vmcnt(6) retires exactly stage(kt) while
// stage(kt+1) stays in flight across the barrier.  At kt == NT-1 only
// stage(NT-1)'s 6 remain -> vmcnt(6) would NOT wait; use vmcnt(0) there
// (block-uniform branch).  Buffer (kt+2)%3 = (kt-1)%3 is free: the barrier
// certifies all waves finished reading it in iter kt-1 (their ds_reads
// completed before the MFMAs that consumed them, which precede the barrier).
// LDS [row][64] u16, XOR swizzle via pre-swizzled global source (rule #21):
// lane covers (row = j*64+w*8+(l>>3), k-slot s=(l&7)^(l>>3)); reads XOR
// byte ^ ((row&7)<<4) -> conflict-free.
// MODE: 0 = u16 C row-major; 1 = f32 C row-major; 2 = K|V split epilogue.
__device__ __forceinline__ void stage_tile2(const u16* Ag, const u16* Bg,
                                            u16* Asb, u16* Bsb, int w, int K,
                                            int k0) {
#pragma unroll
  for (int j = 0; j < 2; ++j)
    load_lds16(Ag + (size_t)j * 64 * K + k0, Asb + j * 4096 + w * 512);
#pragma unroll
  for (int j = 0; j < 4; ++j)
    load_lds16(Bg + (size_t)j * 64 * K + k0, Bsb + j * 4096 + w * 512);
}

template <int MODE>
__global__ __launch_bounds__(512, 2) void gemm2(const u16* __restrict__ A,
                                                const u16* __restrict__ Bt,
                                                void* __restrict__ Cv,
                                                u16* __restrict__ C2,
                                                int K, int ldC) {
  __shared__ __align__(16) u16 As[3][128 * 64];  // 48 KiB
  __shared__ __align__(16) u16 Bs[3][256 * 64];  // 96 KiB
  const int tid = threadIdx.x, lane = tid & 63, w = tid >> 6;
  const int quad = lane >> 4, c16 = lane & 15;
  const int bm = blockIdx.x * 128, bn = blockIdx.y * 256;
  const int wm = (w >> 2) * 64, wn = (w & 3) * 64;

  const int l3 = lane >> 3, l7 = lane & 7;
  const int ss = l7 ^ l3;
  const u16* Ag = A + (size_t)(bm + w * 8 + l3) * K + ss * 8;
  const u16* Bg = Bt + (size_t)(bn + w * 8 + l3) * K + ss * 8;
  const int sx = (c16 & 7) << 4;  // read-side byte XOR

  f32x4 acc[4][4] = {};
  const int NT = K >> 6;

  stage_tile2(Ag, Bg, As[0], Bs[0], w, K, 0);
  stage_tile2(Ag, Bg, As[1], Bs[1], w, K, 64);
  int bc = 0;  // kt % 3
  for (int kt = 0; kt < NT; ++kt) {
    // retire own stage(kt) before joining the barrier; keep stage(kt+1) in
    // flight.  Final iteration has only stage(NT-1) outstanding -> vmcnt(0).
    if (kt < NT - 1)
      asm volatile("s_waitcnt vmcnt(6)" ::: "memory");
    else
      asm volatile("s_waitcnt vmcnt(0)" ::: "memory");
    __builtin_amdgcn_s_barrier();
    asm volatile("" ::: "memory");
    const int bp = bc + 2 >= 3 ? bc - 1 : bc + 2;  // (kt+2) % 3
    if (kt + 2 < NT) stage_tile2(Ag, Bg, As[bp], Bs[bp], w, K, (kt + 2) << 6);

    const u16* Ab = As[bc];
    const u16* Bb = Bs[bc];
    bf16x8 a[4][2], b[4][2];
#pragma unroll
    for (int mt = 0; mt < 4; ++mt)
#pragma unroll
      for (int kc = 0; kc < 2; ++kc) {
        const int row = wm + mt * 16 + c16;
        a[mt][kc] = *(const bf16x8*)&Ab[(row * 128 + ((((kc * 4 + quad) << 4)) ^ sx)) >> 1];
      }
#pragma unroll
    for (int nt = 0; nt < 4; ++nt)
#pragma unroll
      for (int kc = 0; kc < 2; ++kc) {
        const int row = wn + nt * 16 + c16;
        b[nt][kc] = *(const bf16x8*)&Bb[(row * 128 + ((((kc * 4 + quad) << 4)) ^ sx)) >> 1];
      }
    __builtin_amdgcn_s_setprio(1);
#pragma unroll
    for (int kc = 0; kc < 2; ++kc)
#pragma unroll
      for (int mt = 0; mt < 4; ++mt)
#pragma unroll
        for (int nt = 0; nt < 4; ++nt)
          acc[mt][nt] = __builtin_amdgcn_mfma_f32_16x16x32_bf16(a[mt][kc], b[nt][kc], acc[mt][nt], 0, 0, 0);
    __builtin_amdgcn_s_setprio(0);
    bc = bc == 2 ? 0 : bc + 1;
  }
#pragma unroll
  for (int mt = 0; mt < 4; ++mt)
#pragma unroll
    for (int nt = 0; nt < 4; ++nt)
#pragma unroll
      for (int r = 0; r < 4; ++r) {
        const int row = bm + wm + mt * 16 + quad * 4 + r;
        const int col = bn + wn + nt * 16 + c16;
        if (MODE == 1)
          ((float*)Cv)[(size_t)row * ldC + col] = acc[mt][nt][r];
        else if (MODE == 0)
          ((u16*)Cv)[(size_t)row * ldC + col] = f2bf(acc[mt][nt][r]);
        else {  // K|V split: cols <1024 -> Kb row-major; >=1024 -> VTb transposed
          if (bn < 1024)
            ((u16*)Cv)[(size_t)row * 1024 + col] = f2bf(acc[mt][nt][r]);
          else
            C2[(size_t)(col - 1024) * 2048 + row] = f2bf(acc[mt][nt][r]);
        }
      }
}

// ---------------------------------------------------------------- RoPE (in place, bf16)
__global__ void rope_kernel(u16* __restrict__ buf, const int* __restrict__ pos,
                            int log2nh, float oscale) {
  const int t = blockIdx.x * 256 + threadIdx.x;
  const int i = t & 63;
  const int h = (t >> 6) & ((1 << log2nh) - 1);
  const int s = t >> (6 + log2nh);
  const int nh = 1 << log2nh;
  const float p = (float)pos[s];
  const float invf = exp2f((float)i * -0.20762051915861040f);  // 10000^(-i/64)
  const float ang = p * invf;
  const float cn = cosf(ang), sn = sinf(ang);
  const size_t i1 = (size_t)s * (nh * 128) + h * 128 + i;
  const size_t i2 = i1 + 64;
  const float x1 = bf2f(buf[i1]), x2 = bf2f(buf[i2]);
  buf[i1] = f2bf((x1 * cn - x2 * sn) * oscale);
  buf[i2] = f2bf((x2 * cn + x1 * sn) * oscale);
}

// ---------------------------------------------------------------- flash attention
// v4: v3 (unpaired LPT grid, Q direct-to-reg, K/V reg-prefetch, swizzled
// Ks/Vts, setprio) + Ps stride 72->68: scalar u16 P-writes now bank-conflict-
// free (word bank = 8*quad + c16/2 + const, all 32 distinct; S=68 == 4 mod 16).
// Ps reads become 2x ds_read_b64 (8B-aligned, 2-way = free).
__global__ __launch_bounds__(256, 2) void flash_kernel(const u16* __restrict__ Q,
                                                       const u16* __restrict__ K,
                                                       const u16* __restrict__ VT,
                                                       u16* __restrict__ O) {
  __shared__ __align__(16) u16 Ks[64 * 128];   // [key][k], swizzled
  __shared__ __align__(16) u16 Vts[128 * 64];  // [d][key], swizzled
  __shared__ __align__(16) u16 Ps[4][16 * 68]; // per-wave P tile, conflict-free
  const int h = blockIdx.x, kvh = h >> 2;
  const int qb = 31 - blockIdx.y;  // LPT: long blocks first
  const int tid = threadIdx.x, lane = tid & 63, w = tid >> 6;
  const int quad = lane >> 4, c16 = lane & 15;
  const int rw = lane >> 2, c4 = lane & 3;
  const int sw = (rw & 7) << 3;
  const int sr = (c16 & 7) << 3;

  bf16x8 aq[4];
#pragma unroll
  for (int kc = 0; kc < 4; ++kc)
    aq[kc] = *(const bf16x8*)&Q[(size_t)(qb * 64 + w * 16 + c16) * 4096 + h * 128 + kc * 32 + quad * 8];

  f32x4 acc_o[8] = {};
  float m_run[4], l_run[4];
#pragma unroll
  for (int r = 0; r < 4; ++r) { m_run[r] = -1e30f; l_run[r] = 0.f; }

  bf16x8 kc_[4], vc_[4];
#pragma unroll
  for (int p = 0; p < 4; ++p) {
    kc_[p] = *(const bf16x8*)&K[(size_t)(w * 16 + rw) * 1024 + kvh * 128 + p * 32 + c4 * 8];
    const int d = (p & 1) * 64 + w * 16 + rw;
    vc_[p] = *(const bf16x8*)&VT[(size_t)(kvh * 128 + d) * 2048 + (p >> 1) * 32 + c4 * 8];
  }

  for (int t = 0; t <= qb; ++t) {
    __syncthreads();
    const int key = w * 16 + rw;
#pragma unroll
    for (int p = 0; p < 4; ++p) {
      *(bf16x8*)&Ks[key * 128 + ((p * 32 + c4 * 8) ^ sw)] = kc_[p];
      const int d = (p & 1) * 64 + w * 16 + rw;
      *(bf16x8*)&Vts[d * 64 + ((((p >> 1) * 32 + c4 * 8)) ^ ((d & 7) << 3))] = vc_[p];
    }
    __syncthreads();
    if (t < qb) {
#pragma unroll
      for (int p = 0; p < 4; ++p) {
        kc_[p] = *(const bf16x8*)&K[(size_t)((t + 1) * 64 + w * 16 + rw) * 1024 + kvh * 128 + p * 32 + c4 * 8];
        const int d = (p & 1) * 64 + w * 16 + rw;
        vc_[p] = *(const bf16x8*)&VT[(size_t)(kvh * 128 + d) * 2048 + (t + 1) * 64 + (p >> 1) * 32 + c4 * 8];
      }
    }

    f32x4 sacc[4];
    __builtin_amdgcn_s_setprio(1);
#pragma unroll
    for (int nt = 0; nt < 4; ++nt) {
      f32x4 s = {0.f, 0.f, 0.f, 0.f};
#pragma unroll
      for (int kc = 0; kc < 4; ++kc) {
        bf16x8 bk = *(const bf16x8*)&Ks[(nt * 16 + c16) * 128 + ((kc * 32 + quad * 8) ^ sr)];
        s = __builtin_amdgcn_mfma_f32_16x16x32_bf16(aq[kc], bk, s, 0, 0, 0);
      }
      sacc[nt] = s;
    }
    __builtin_amdgcn_s_setprio(0);
    if (t == qb) {
#pragma unroll
      for (int nt = 0; nt < 4; ++nt)
#pragma unroll
        for (int r = 0; r < 4; ++r)
          if (nt * 16 + c16 > w * 16 + quad * 4 + r) sacc[nt][r] = -1e30f;
    }
    float al[4];
#pragma unroll
    for (int r = 0; r < 4; ++r) {
      float mx = fmaxf(fmaxf(sacc[0][r], sacc[1][r]), fmaxf(sacc[2][r], sacc[3][r]));
#pragma unroll
      for (int off = 1; off < 16; off <<= 1) mx = fmaxf(mx, __shfl_xor(mx, off));
      const float nm = fmaxf(m_run[r], mx);
      al[r] = __expf(m_run[r] - nm);
      m_run[r] = nm;
      float sum = 0.f;
#pragma unroll
      for (int nt = 0; nt < 4; ++nt) {
        const float pv = __expf(sacc[nt][r] - nm);
        sacc[nt][r] = pv;
        sum += pv;
      }
#pragma unroll
      for (int off = 1; off < 16; off <<= 1) sum += __shfl_xor(sum, off);
      l_run[r] = l_run[r] * al[r] + sum;
    }
#pragma unroll
    for (int dt = 0; dt < 8; ++dt)
#pragma unroll
      for (int r = 0; r < 4; ++r) acc_o[dt][r] *= al[r];
#pragma unroll
    for (int nt = 0; nt < 4; ++nt)
#pragma unroll
      for (int r = 0; r < 4; ++r)
        Ps[w][(quad * 4 + r) * 68 + nt * 16 + c16] = f2bf(sacc[nt][r]);
    asm volatile("s_waitcnt lgkmcnt(0)" ::: "memory");
    bf16x8 ap[2];
#pragma unroll
    for (int kc = 0; kc < 2; ++kc) {
      const u16* pp = &Ps[w][c16 * 68 + kc * 32 + quad * 8];
      bf16x4 lo = *(const bf16x4*)pp;
      bf16x4 hi = *(const bf16x4*)(pp + 4);
      bf16x8 apv;
#pragma unroll
      for (int j = 0; j < 4; ++j) { apv[j] = lo[j]; apv[4 + j] = hi[j]; }
      ap[kc] = apv;
    }
    __builtin_amdgcn_s_setprio(1);
#pragma unroll
    for (int dt = 0; dt < 8; ++dt)
#pragma unroll
      for (int kc = 0; kc < 2; ++kc) {
        bf16x8 bv = *(const bf16x8*)&Vts[(dt * 16 + c16) * 64 + ((kc * 32 + quad * 8) ^ sr)];
        acc_o[dt] = __builtin_amdgcn_mfma_f32_16x16x32_bf16(ap[kc], bv, acc_o[dt], 0, 0, 0);
      }
    __builtin_amdgcn_s_setprio(0);
  }
#pragma unroll
  for (int r = 0; r < 4; ++r) {
    const float inv = 1.0f / l_run[r];
    const int row = qb * 64 + w * 16 + quad * 4 + r;
#pragma unroll
    for (int dt = 0; dt < 8; ++dt)
      O[(size_t)row * 4096 + h * 128 + dt * 16 + c16] = f2bf(acc_o[dt][r] * inv);
  }
}

// ---------------------------------------------------------------- launch
extern "C" void kernel_launch(void* const* d_in, const int* in_sizes, int n_in,
                              void* d_out, int out_size, void* d_ws, size_t ws_size,
                              hipStream_t stream) {
  const float* X  = (const float*)d_in[0];   // [2048,4096] f32
  const int* pos  = (const int*)d_in[2];     // causal mask (d_in[1]) applied analytically
  const float* Wq = (const float*)d_in[3];   // [4096,4096] f32
  const float* Wk = (const float*)d_in[4];   // [4096,1024] f32
  const float* Wv = (const float*)d_in[5];   // [4096,1024] f32
  const float* Wo = (const float*)d_in[6];   // [4096,4096] f32
  float* out = (float*)d_out;                // [2048,4096] f32

  // ws layout (big): WT 32MB @0, Att 16MB @32M.  small: WT 16MB @0, Att @16M.
  // Xb (bf16 X, 16MB) shares the Att slot — dead before flash writes Att.
  const int NP = (ws_size >= (size_t)50331648) ? 4096 : 2048;  // weight-panel width
  char* ws = (char*)d_ws;
  u16* WT  = (u16*)ws;
  u16* Att = (u16*)(ws + (NP == 4096 ? 33554432 : 16777216));
  u16* Xb  = Att;
  // d_out hosts bf16 intermediates until gemmO overwrites it (stream-ordered):
  u16* Qb  = (u16*)d_out;                    // 16 MB
  u16* Kb  = (u16*)((char*)d_out + 16777216);  // 4 MB
  u16* VTb = (u16*)((char*)d_out + 20971520);  // 4 MB (V^T [1024][2048])

  const dim3 b256(256), b512(512);

  // X -> bf16 once (A operand for all projections)
  cvt_bf16_kernel<<<dim3(4096), b256, 0, stream>>>(X, Xb);

  // Q projection (panelled over N)
  for (int p = 0; p < 4096; p += NP) {
    transpose_w<<<dim3(NP / 32, 128), b256, 0, stream>>>(Wq, WT, 4096, 4096, p);
    gemm2<0><<<dim3(16, NP / 256), b512, 0, stream>>>(Xb, WT, Qb + p, nullptr, 4096, 4096);
  }
  // K|V fused projection: WT rows 0..1023 = Wk^T, rows 1024..2047 = Wv^T
  transpose_w<<<dim3(32, 128), b256, 0, stream>>>(Wk, WT, 4096, 1024, 0);
  transpose_w<<<dim3(32, 128), b256, 0, stream>>>(Wv, WT + (size_t)1024 * 4096, 4096, 1024, 0);
  gemm2<2><<<dim3(16, 8), b512, 0, stream>>>(Xb, WT, Kb, VTb, 4096, 0);

  // RoPE (Q pre-scaled by 1/sqrt(128))
  rope_kernel<<<dim3(2048 * 32 * 64 / 256), b256, 0, stream>>>(Qb, pos, 5, 0.08838834764831845f);
  rope_kernel<<<dim3(2048 * 8 * 64 / 256),  b256, 0, stream>>>(Kb, pos, 3, 1.0f);

  // unpaired LPT grid: x = head, y: qb = 31 - y -> longest blocks first
  flash_kernel<<<dim3(32, 32), b256, 0, stream>>>(Qb, Kb, VTb, Att);

  // O projection (reads Att bf16 + WT panels, writes f32 out)
  for (int p = 0; p < 4096; p += NP) {
    transpose_w<<<dim3(NP / 32, 128), b256, 0, stream>>>(Wo, WT, 4096, 4096, p);
    gemm2<1><<<dim3(16, NP / 256), b512, 0, stream>>>(Att, WT, out + p, nullptr, 4096, 4096);
  }
}

// Round 10
// 607.973 us; speedup vs baseline: 1.0011x; 1.0011x over previous
//
#include <hip/hip_runtime.h>

typedef unsigned short u16;
typedef __attribute__((ext_vector_type(8))) __bf16 bf16x8;
typedef __attribute__((ext_vector_type(4))) __bf16 bf16x4;
typedef __attribute__((ext_vector_type(8))) unsigned short u16x8;
typedef __attribute__((ext_vector_type(4))) unsigned short u16x4;
typedef __attribute__((ext_vector_type(4))) float f32x4;

#define AS1 __attribute__((address_space(1)))
#define AS3 __attribute__((address_space(3)))

__device__ __forceinline__ void load_lds16(const void* g, void* l) {
  __builtin_amdgcn_global_load_lds((const AS1 unsigned int*)g,
                                   (AS3 unsigned int*)l, 16, 0, 0);
}

__device__ __forceinline__ float bf2f(u16 u) {
  unsigned int x = ((unsigned int)u) << 16;
  return __builtin_bit_cast(float, x);
}
__device__ __forceinline__ u16 f2bf(float f) {
  unsigned int x = __builtin_bit_cast(unsigned int, f);
  x += 0x7fffu + ((x >> 16) & 1u);
  return (u16)(x >> 16);
}
// load 8 consecutive f32, RNE-convert to bf16x8
__device__ __forceinline__ bf16x8 cvt8(const float* p) {
  f32x4 a = *(const f32x4*)p;
  f32x4 b = *(const f32x4*)(p + 4);
  u16x8 r;
#pragma unroll
  for (int j = 0; j < 4; ++j) { r[j] = f2bf(a[j]); r[4 + j] = f2bf(b[j]); }
  return __builtin_bit_cast(bf16x8, r);
}

// ---------------------------------------------------------------- f32 -> bf16 bulk convert
__global__ __launch_bounds__(256) void cvt_bf16_kernel(const float* __restrict__ in,
                                                       u16* __restrict__ out) {
  const int i = (blockIdx.x * 256 + threadIdx.x) * 8;
  *(bf16x8*)&out[i] = cvt8(in + i);
}

// ---------------------------------------------------------------- weight transpose (v1, verified)
// out[c - col0][r] = bf16(in[r*C + c])  for c in [col0, col0+Cpanel)
// 32x33-padded LDS tile: conflict-free.
__global__ __launch_bounds__(256) void transpose_w(const float* __restrict__ in,
                                                   u16* __restrict__ out,
                                                   int R, int C, int col0) {
  __shared__ u16 tile[32][33];
  const int tx = threadIdx.x & 31, ty = threadIdx.x >> 5;
  const int c0 = blockIdx.x * 32, r0 = blockIdx.y * 32;  // c0: panel-local col
#pragma unroll
  for (int j = ty; j < 32; j += 8)
    tile[j][tx] = f2bf(in[(size_t)(r0 + j) * C + col0 + c0 + tx]);
  __syncthreads();
#pragma unroll
  for (int j = ty; j < 32; j += 8)
    out[(size_t)(c0 + j) * R + r0 + tx] = tile[tx][j];
}

// ---------------------------------------------------------------- GEMM (deep pipeline, T4 + T1)
// C[M,N] = A[M,K] @ Bt[N,K]^T, A,Bt bf16.  BM=128, BN=256, BK=64, 512 thr =
// 8 waves (2M x 4N, wave owns 64x64).  Triple-buffered LDS (144 KiB), counted
// vmcnt (per-CU neutral vs syncthreads — measured r5 vs r8 — kept as-is).
// T1 XCD swizzle: dispatch round-robins flat blockIdx over 8 XCDs; remap so
// all blocks sharing a bn (B-panel, 2 MB) land on ONE XCD -> B-panel L2-
// resident there instead of fetched by all 8 XCDs.  Bijective per grid shape:
//   gy==16: xcd=f&7 hosts bn in {2*xcd, 2*xcd+1}; bm = f>>4
//   gy==8 : xcd=f&7 hosts bn == xcd;             bm = f>>3
// LDS [row][64] u16, XOR swizzle via pre-swizzled global source (rule #21).
// MODE: 0 = u16 C row-major; 1 = f32 C row-major; 2 = K|V split epilogue.
__device__ __forceinline__ void stage_tile2(const u16* Ag, const u16* Bg,
                                            u16* Asb, u16* Bsb, int w, int K,
                                            int k0) {
#pragma unroll
  for (int j = 0; j < 2; ++j)
    load_lds16(Ag + (size_t)j * 64 * K + k0, Asb + j * 4096 + w * 512);
#pragma unroll
  for (int j = 0; j < 4; ++j)
    load_lds16(Bg + (size_t)j * 64 * K + k0, Bsb + j * 4096 + w * 512);
}

template <int MODE>
__global__ __launch_bounds__(512, 2) void gemm2(const u16* __restrict__ A,
                                                const u16* __restrict__ Bt,
                                                void* __restrict__ Cv,
                                                u16* __restrict__ C2,
                                                int K, int ldC) {
  __shared__ __align__(16) u16 As[3][128 * 64];  // 48 KiB
  __shared__ __align__(16) u16 Bs[3][256 * 64];  // 96 KiB
  const int tid = threadIdx.x, lane = tid & 63, w = tid >> 6;
  const int quad = lane >> 4, c16 = lane & 15;

  // T1 XCD-aware remap (block-uniform, bijective)
  const int f = blockIdx.y * gridDim.x + blockIdx.x;
  int bm, bn;
  if (gridDim.y == 16) { bn = ((f & 7) * 2 + ((f >> 3) & 1)) * 256; bm = (f >> 4) * 128; }
  else                 { bn = (f & 7) * 256;                        bm = (f >> 3) * 128; }

  const int wm = (w >> 2) * 64, wn = (w & 3) * 64;

  const int l3 = lane >> 3, l7 = lane & 7;
  const int ss = l7 ^ l3;
  const u16* Ag = A + (size_t)(bm + w * 8 + l3) * K + ss * 8;
  const u16* Bg = Bt + (size_t)(bn + w * 8 + l3) * K + ss * 8;
  const int sx = (c16 & 7) << 4;  // read-side byte XOR

  f32x4 acc[4][4] = {};
  const int NT = K >> 6;

  stage_tile2(Ag, Bg, As[0], Bs[0], w, K, 0);
  stage_tile2(Ag, Bg, As[1], Bs[1], w, K, 64);
  int bc = 0;  // kt % 3
  for (int kt = 0; kt < NT; ++kt) {
    // retire own stage(kt) before joining the barrier; keep stage(kt+1) in
    // flight.  Final iteration has only stage(NT-1) outstanding -> vmcnt(0).
    if (kt < NT - 1)
      asm volatile("s_waitcnt vmcnt(6)" ::: "memory");
    else
      asm volatile("s_waitcnt vmcnt(0)" ::: "memory");
    __builtin_amdgcn_s_barrier();
    asm volatile("" ::: "memory");
    const int bp = bc + 2 >= 3 ? bc - 1 : bc + 2;  // (kt+2) % 3
    if (kt + 2 < NT) stage_tile2(Ag, Bg, As[bp], Bs[bp], w, K, (kt + 2) << 6);

    const u16* Ab = As[bc];
    const u16* Bb = Bs[bc];
    bf16x8 a[4][2], b[4][2];
#pragma unroll
    for (int mt = 0; mt < 4; ++mt)
#pragma unroll
      for (int kc = 0; kc < 2; ++kc) {
        const int row = wm + mt * 16 + c16;
        a[mt][kc] = *(const bf16x8*)&Ab[(row * 128 + ((((kc * 4 + quad) << 4)) ^ sx)) >> 1];
      }
#pragma unroll
    for (int nt = 0; nt < 4; ++nt)
#pragma unroll
      for (int kc = 0; kc < 2; ++kc) {
        const int row = wn + nt * 16 + c16;
        b[nt][kc] = *(const bf16x8*)&Bb[(row * 128 + ((((kc * 4 + quad) << 4)) ^ sx)) >> 1];
      }
    __builtin_amdgcn_s_setprio(1);
#pragma unroll
    for (int kc = 0; kc < 2; ++kc)
#pragma unroll
      for (int mt = 0; mt < 4; ++mt)
#pragma unroll
        for (int nt = 0; nt < 4; ++nt)
          acc[mt][nt] = __builtin_amdgcn_mfma_f32_16x16x32_bf16(a[mt][kc], b[nt][kc], acc[mt][nt], 0, 0, 0);
    __builtin_amdgcn_s_setprio(0);
    bc = bc == 2 ? 0 : bc + 1;
  }
#pragma unroll
  for (int mt = 0; mt < 4; ++mt)
#pragma unroll
    for (int nt = 0; nt < 4; ++nt)
#pragma unroll
      for (int r = 0; r < 4; ++r) {
        const int row = bm + wm + mt * 16 + quad * 4 + r;
        const int col = bn + wn + nt * 16 + c16;
        if (MODE == 1)
          ((float*)Cv)[(size_t)row * ldC + col] = acc[mt][nt][r];
        else if (MODE == 0)
          ((u16*)Cv)[(size_t)row * ldC + col] = f2bf(acc[mt][nt][r]);
        else {  // K|V split: cols <1024 -> Kb row-major; >=1024 -> VTb transposed
          if (bn < 1024)
            ((u16*)Cv)[(size_t)row * 1024 + col] = f2bf(acc[mt][nt][r]);
          else
            C2[(size_t)(col - 1024) * 2048 + row] = f2bf(acc[mt][nt][r]);
        }
      }
}

// ---------------------------------------------------------------- RoPE (in place, bf16)
__global__ void rope_kernel(u16* __restrict__ buf, const int* __restrict__ pos,
                            int log2nh, float oscale) {
  const int t = blockIdx.x * 256 + threadIdx.x;
  const int i = t & 63;
  const int h = (t >> 6) & ((1 << log2nh) - 1);
  const int s = t >> (6 + log2nh);
  const int nh = 1 << log2nh;
  const float p = (float)pos[s];
  const float invf = exp2f((float)i * -0.20762051915861040f);  // 10000^(-i/64)
  const float ang = p * invf;
  const float cn = cosf(ang), sn = sinf(ang);
  const size_t i1 = (size_t)s * (nh * 128) + h * 128 + i;
  const size_t i2 = i1 + 64;
  const float x1 = bf2f(buf[i1]), x2 = bf2f(buf[i2]);
  buf[i1] = f2bf((x1 * cn - x2 * sn) * oscale);
  buf[i2] = f2bf((x2 * cn + x1 * sn) * oscale);
}

// ---------------------------------------------------------------- flash attention
// v4 (verified r8): unpaired LPT grid, Q direct-to-reg, K/V reg-prefetch,
// swizzled Ks/Vts, setprio, Ps stride 68 (conflict-free scalar P-writes).
__global__ __launch_bounds__(256, 2) void flash_kernel(const u16* __restrict__ Q,
                                                       const u16* __restrict__ K,
                                                       const u16* __restrict__ VT,
                                                       u16* __restrict__ O) {
  __shared__ __align__(16) u16 Ks[64 * 128];   // [key][k], swizzled
  __shared__ __align__(16) u16 Vts[128 * 64];  // [d][key], swizzled
  __shared__ __align__(16) u16 Ps[4][16 * 68]; // per-wave P tile, conflict-free
  const int h = blockIdx.x, kvh = h >> 2;
  const int qb = 31 - blockIdx.y;  // LPT: long blocks first
  const int tid = threadIdx.x, lane = tid & 63, w = tid >> 6;
  const int quad = lane >> 4, c16 = lane & 15;
  const int rw = lane >> 2, c4 = lane & 3;
  const int sw = (rw & 7) << 3;
  const int sr = (c16 & 7) << 3;

  bf16x8 aq[4];
#pragma unroll
  for (int kc = 0; kc < 4; ++kc)
    aq[kc] = *(const bf16x8*)&Q[(size_t)(qb * 64 + w * 16 + c16) * 4096 + h * 128 + kc * 32 + quad * 8];

  f32x4 acc_o[8] = {};
  float m_run[4], l_run[4];
#pragma unroll
  for (int r = 0; r < 4; ++r) { m_run[r] = -1e30f; l_run[r] = 0.f; }

  bf16x8 kc_[4], vc_[4];
#pragma unroll
  for (int p = 0; p < 4; ++p) {
    kc_[p] = *(const bf16x8*)&K[(size_t)(w * 16 + rw) * 1024 + kvh * 128 + p * 32 + c4 * 8];
    const int d = (p & 1) * 64 + w * 16 + rw;
    vc_[p] = *(const bf16x8*)&VT[(size_t)(kvh * 128 + d) * 2048 + (p >> 1) * 32 + c4 * 8];
  }

  for (int t = 0; t <= qb; ++t) {
    __syncthreads();
    const int key = w * 16 + rw;
#pragma unroll
    for (int p = 0; p < 4; ++p) {
      *(bf16x8*)&Ks[key * 128 + ((p * 32 + c4 * 8) ^ sw)] = kc_[p];
      const int d = (p & 1) * 64 + w * 16 + rw;
      *(bf16x8*)&Vts[d * 64 + ((((p >> 1) * 32 + c4 * 8)) ^ ((d & 7) << 3))] = vc_[p];
    }
    __syncthreads();
    if (t < qb) {
#pragma unroll
      for (int p = 0; p < 4; ++p) {
        kc_[p] = *(const bf16x8*)&K[(size_t)((t + 1) * 64 + w * 16 + rw) * 1024 + kvh * 128 + p * 32 + c4 * 8];
        const int d = (p & 1) * 64 + w * 16 + rw;
        vc_[p] = *(const bf16x8*)&VT[(size_t)(kvh * 128 + d) * 2048 + (t + 1) * 64 + (p >> 1) * 32 + c4 * 8];
      }
    }

    f32x4 sacc[4];
    __builtin_amdgcn_s_setprio(1);
#pragma unroll
    for (int nt = 0; nt < 4; ++nt) {
      f32x4 s = {0.f, 0.f, 0.f, 0.f};
#pragma unroll
      for (int kc = 0; kc < 4; ++kc) {
        bf16x8 bk = *(const bf16x8*)&Ks[(nt * 16 + c16) * 128 + ((kc * 32 + quad * 8) ^ sr)];
        s = __builtin_amdgcn_mfma_f32_16x16x32_bf16(aq[kc], bk, s, 0, 0, 0);
      }
      sacc[nt] = s;
    }
    __builtin_amdgcn_s_setprio(0);
    if (t == qb) {
#pragma unroll
      for (int nt = 0; nt < 4; ++nt)
#pragma unroll
        for (int r = 0; r < 4; ++r)
          if (nt * 16 + c16 > w * 16 + quad * 4 + r) sacc[nt][r] = -1e30f;
    }
    float al[4];
#pragma unroll
    for (int r = 0; r < 4; ++r) {
      float mx = fmaxf(fmaxf(sacc[0][r], sacc[1][r]), fmaxf(sacc[2][r], sacc[3][r]));
#pragma unroll
      for (int off = 1; off < 16; off <<= 1) mx = fmaxf(mx, __shfl_xor(mx, off));
      const float nm = fmaxf(m_run[r], mx);
      al[r] = __expf(m_run[r] - nm);
      m_run[r] = nm;
      float sum = 0.f;
#pragma unroll
      for (int nt = 0; nt < 4; ++nt) {
        const float pv = __expf(sacc[nt][r] - nm);
        sacc[nt][r] = pv;
        sum += pv;
      }
#pragma unroll
      for (int off = 1; off < 16; off <<= 1) sum += __shfl_xor(sum, off);
      l_run[r] = l_run[r] * al[r] + sum;
    }
#pragma unroll
    for (int dt = 0; dt < 8; ++dt)
#pragma unroll
      for (int r = 0; r < 4; ++r) acc_o[dt][r] *= al[r];
#pragma unroll
    for (int nt = 0; nt < 4; ++nt)
#pragma unroll
      for (int r = 0; r < 4; ++r)
        Ps[w][(quad * 4 + r) * 68 + nt * 16 + c16] = f2bf(sacc[nt][r]);
    asm volatile("s_waitcnt lgkmcnt(0)" ::: "memory");
    bf16x8 ap[2];
#pragma unroll
    for (int kc = 0; kc < 2; ++kc) {
      const u16* pp = &Ps[w][c16 * 68 + kc * 32 + quad * 8];
      bf16x4 lo = *(const bf16x4*)pp;
      bf16x4 hi = *(const bf16x4*)(pp + 4);
      bf16x8 apv;
#pragma unroll
      for (int j = 0; j < 4; ++j) { apv[j] = lo[j]; apv[4 + j] = hi[j]; }
      ap[kc] = apv;
    }
    __builtin_amdgcn_s_setprio(1);
#pragma unroll
    for (int dt = 0; dt < 8; ++dt)
#pragma unroll
      for (int kc = 0; kc < 2; ++kc) {
        bf16x8 bv = *(const bf16x8*)&Vts[(dt * 16 + c16) * 64 + ((kc * 32 + quad * 8) ^ sr)];
        acc_o[dt] = __builtin_amdgcn_mfma_f32_16x16x32_bf16(ap[kc], bv, acc_o[dt], 0, 0, 0);
      }
    __builtin_amdgcn_s_setprio(0);
  }
#pragma unroll
  for (int r = 0; r < 4; ++r) {
    const float inv = 1.0f / l_run[r];
    const int row = qb * 64 + w * 16 + quad * 4 + r;
#pragma unroll
    for (int dt = 0; dt < 8; ++dt)
      O[(size_t)row * 4096 + h * 128 + dt * 16 + c16] = f2bf(acc_o[dt][r] * inv);
  }
}

// ---------------------------------------------------------------- launch
extern "C" void kernel_launch(void* const* d_in, const int* in_sizes, int n_in,
                              void* d_out, int out_size, void* d_ws, size_t ws_size,
                              hipStream_t stream) {
  const float* X  = (const float*)d_in[0];   // [2048,4096] f32
  const int* pos  = (const int*)d_in[2];     // causal mask (d_in[1]) applied analytically
  const float* Wq = (const float*)d_in[3];   // [4096,4096] f32
  const float* Wk = (const float*)d_in[4];   // [4096,1024] f32
  const float* Wv = (const float*)d_in[5];   // [4096,1024] f32
  const float* Wo = (const float*)d_in[6];   // [4096,4096] f32
  float* out = (float*)d_out;                // [2048,4096] f32

  // ws_size is fixed per session -> branch deterministic (graph-safe).
  // BIG  (ws>=48M): WT 32M @ws0 (live all phases), Att/Xb @ws+32M,
  //                 Qb @dout0, Kb @dout+16M, VTb @dout+20M.  Q,O full launches.
  // SMALL(ws>=32M): Xb @dout0, Qb @dout+16M (both dead before out written);
  //                 WT_q = ws FULL 32M -> Q is ONE full-machine launch;
  //                 WT_kv @ws0 16M (WT_q dead), Kb @ws+16M, VTb @ws+20M;
  //                 Att @ws0 (WT_kv dead, disjoint from Kb/VTb);
  //                 O: 2 panels, WT_o @ws+16M (Kb/VTb dead).
  const int big = ws_size >= (size_t)50331648;
  char* ws = (char*)d_ws;
  u16* WTq  = (u16*)ws;                      // 32 MB, both paths
  u16* WTkv = (u16*)ws;                      // 16 MB, both paths (WTq dead)
  u16* Att, *Xb, *Qb, *Kb, *VTb, *WTo;
  int NPo;
  if (big) {
    Att = (u16*)(ws + 33554432);
    Xb  = Att;                               // dead before flash writes Att
    Qb  = (u16*)d_out;
    Kb  = (u16*)((char*)d_out + 16777216);
    VTb = (u16*)((char*)d_out + 20971520);
    WTo = (u16*)ws;                          // full 32 MB
    NPo = 4096;
  } else {
    Att = (u16*)ws;                          // WTkv dead by flash time
    Xb  = (u16*)d_out;                       // dead after K|V gemm
    Qb  = (u16*)((char*)d_out + 16777216);   // dead after flash
    Kb  = (u16*)(ws + 16777216);             // dead after flash
    VTb = (u16*)(ws + 20971520);
    WTo = (u16*)(ws + 16777216);             // 16 MB panels (Kb/VTb dead)
    NPo = 2048;
  }

  const dim3 b256(256), b512(512);

  // X -> bf16 once (A operand for all projections)
  cvt_bf16_kernel<<<dim3(4096), b256, 0, stream>>>(X, Xb);

  // Q projection: ONE full-machine launch in both paths (WT_q = 32 MB)
  transpose_w<<<dim3(128, 128), b256, 0, stream>>>(Wq, WTq, 4096, 4096, 0);
  gemm2<0><<<dim3(16, 16), b512, 0, stream>>>(Xb, WTq, Qb, nullptr, 4096, 4096);

  // K|V fused projection: WTkv rows 0..1023 = Wk^T, rows 1024..2047 = Wv^T
  transpose_w<<<dim3(32, 128), b256, 0, stream>>>(Wk, WTkv, 4096, 1024, 0);
  transpose_w<<<dim3(32, 128), b256, 0, stream>>>(Wv, WTkv + (size_t)1024 * 4096, 4096, 1024, 0);
  gemm2<2><<<dim3(16, 8), b512, 0, stream>>>(Xb, WTkv, Kb, VTb, 4096, 0);

  // RoPE (Q pre-scaled by 1/sqrt(128))
  rope_kernel<<<dim3(2048 * 32 * 64 / 256), b256, 0, stream>>>(Qb, pos, 5, 0.08838834764831845f);
  rope_kernel<<<dim3(2048 * 8 * 64 / 256),  b256, 0, stream>>>(Kb, pos, 3, 1.0f);

  // unpaired LPT grid: x = head, y: qb = 31 - y -> longest blocks first
  flash_kernel<<<dim3(32, 32), b256, 0, stream>>>(Qb, Kb, VTb, Att);

  // O projection (reads Att bf16 + WTo panels, writes f32 out)
  for (int p = 0; p < 4096; p += NPo) {
    transpose_w<<<dim3(NPo / 32, 128), b256, 0, stream>>>(Wo, WTo, 4096, 4096, p);
    gemm2<1><<<dim3(16, NPo / 256), b512, 0, stream>>>(Att, WTo, out + p, nullptr, 4096, 4096);
  }
}

// Round 11
// 577.817 us; speedup vs baseline: 1.0534x; 1.0522x over previous
//
#include <hip/hip_runtime.h>

typedef unsigned short u16;
typedef __attribute__((ext_vector_type(8))) __bf16 bf16x8;
typedef __attribute__((ext_vector_type(4))) __bf16 bf16x4;
typedef __attribute__((ext_vector_type(8))) unsigned short u16x8;
typedef __attribute__((ext_vector_type(4))) unsigned short u16x4;
typedef __attribute__((ext_vector_type(4))) float f32x4;

#define AS1 __attribute__((address_space(1)))
#define AS3 __attribute__((address_space(3)))

__device__ __forceinline__ void load_lds16(const void* g, void* l) {
  __builtin_amdgcn_global_load_lds((const AS1 unsigned int*)g,
                                   (AS3 unsigned int*)l, 16, 0, 0);
}

__device__ __forceinline__ float bf2f(u16 u) {
  unsigned int x = ((unsigned int)u) << 16;
  return __builtin_bit_cast(float, x);
}
__device__ __forceinline__ u16 f2bf(float f) {
  unsigned int x = __builtin_bit_cast(unsigned int, f);
  x += 0x7fffu + ((x >> 16) & 1u);
  return (u16)(x >> 16);
}
// load 8 consecutive f32, RNE-convert to bf16x8
__device__ __forceinline__ bf16x8 cvt8(const float* p) {
  f32x4 a = *(const f32x4*)p;
  f32x4 b = *(const f32x4*)(p + 4);
  u16x8 r;
#pragma unroll
  for (int j = 0; j < 4; ++j) { r[j] = f2bf(a[j]); r[4 + j] = f2bf(b[j]); }
  return __builtin_bit_cast(bf16x8, r);
}

// ---------------------------------------------------------------- f32 -> bf16 bulk convert
__global__ __launch_bounds__(256) void cvt_bf16_kernel(const float* __restrict__ in,
                                                       u16* __restrict__ out) {
  const int i = (blockIdx.x * 256 + threadIdx.x) * 8;
  *(bf16x8*)&out[i] = cvt8(in + i);
}

// ---------------------------------------------------------------- weight transpose (v1, verified)
// out[c - col0][r] = bf16(in[r*C + c])  for c in [col0, col0+Cpanel)
// 32x33-padded LDS tile: conflict-free.
__global__ __launch_bounds__(256) void transpose_w(const float* __restrict__ in,
                                                   u16* __restrict__ out,
                                                   int R, int C, int col0) {
  __shared__ u16 tile[32][33];
  const int tx = threadIdx.x & 31, ty = threadIdx.x >> 5;
  const int c0 = blockIdx.x * 32, r0 = blockIdx.y * 32;  // c0: panel-local col
#pragma unroll
  for (int j = ty; j < 32; j += 8)
    tile[j][tx] = f2bf(in[(size_t)(r0 + j) * C + col0 + c0 + tx]);
  __syncthreads();
#pragma unroll
  for (int j = ty; j < 32; j += 8)
    out[(size_t)(c0 + j) * R + r0 + tx] = tile[tx][j];
}

// ---------------------------------------------------------------- gemm2 (r8-verified, control arm)
// BM=128, BN=256, BK=64, 512 thr, triple-buffer 144 KiB (1 block/CU), counted
// vmcnt.  Per-CU staging rate measured ~31 GB/s/CU (1 block/CU: barrier drain
// stalls the CU's DMA pipe).  Kept for KV + small-ws O while gemm3 tests the
// 2-blocks/CU hypothesis on Q.
__device__ __forceinline__ void stage_tile2(const u16* Ag, const u16* Bg,
                                            u16* Asb, u16* Bsb, int w, int K,
                                            int k0) {
#pragma unroll
  for (int j = 0; j < 2; ++j)
    load_lds16(Ag + (size_t)j * 64 * K + k0, Asb + j * 4096 + w * 512);
#pragma unroll
  for (int j = 0; j < 4; ++j)
    load_lds16(Bg + (size_t)j * 64 * K + k0, Bsb + j * 4096 + w * 512);
}

template <int MODE>
__global__ __launch_bounds__(512, 2) void gemm2(const u16* __restrict__ A,
                                                const u16* __restrict__ Bt,
                                                void* __restrict__ Cv,
                                                u16* __restrict__ C2,
                                                int K, int ldC) {
  __shared__ __align__(16) u16 As[3][128 * 64];  // 48 KiB
  __shared__ __align__(16) u16 Bs[3][256 * 64];  // 96 KiB
  const int tid = threadIdx.x, lane = tid & 63, w = tid >> 6;
  const int quad = lane >> 4, c16 = lane & 15;
  const int bm = blockIdx.x * 128, bn = blockIdx.y * 256;
  const int wm = (w >> 2) * 64, wn = (w & 3) * 64;

  const int l3 = lane >> 3, l7 = lane & 7;
  const int ss = l7 ^ l3;
  const u16* Ag = A + (size_t)(bm + w * 8 + l3) * K + ss * 8;
  const u16* Bg = Bt + (size_t)(bn + w * 8 + l3) * K + ss * 8;
  const int sx = (c16 & 7) << 4;  // read-side byte XOR

  f32x4 acc[4][4] = {};
  const int NT = K >> 6;

  stage_tile2(Ag, Bg, As[0], Bs[0], w, K, 0);
  stage_tile2(Ag, Bg, As[1], Bs[1], w, K, 64);
  int bc = 0;  // kt % 3
  for (int kt = 0; kt < NT; ++kt) {
    if (kt < NT - 1)
      asm volatile("s_waitcnt vmcnt(6)" ::: "memory");
    else
      asm volatile("s_waitcnt vmcnt(0)" ::: "memory");
    __builtin_amdgcn_s_barrier();
    asm volatile("" ::: "memory");
    const int bp = bc + 2 >= 3 ? bc - 1 : bc + 2;  // (kt+2) % 3
    if (kt + 2 < NT) stage_tile2(Ag, Bg, As[bp], Bs[bp], w, K, (kt + 2) << 6);

    const u16* Ab = As[bc];
    const u16* Bb = Bs[bc];
    bf16x8 a[4][2], b[4][2];
#pragma unroll
    for (int mt = 0; mt < 4; ++mt)
#pragma unroll
      for (int kc = 0; kc < 2; ++kc) {
        const int row = wm + mt * 16 + c16;
        a[mt][kc] = *(const bf16x8*)&Ab[(row * 128 + ((((kc * 4 + quad) << 4)) ^ sx)) >> 1];
      }
#pragma unroll
    for (int nt = 0; nt < 4; ++nt)
#pragma unroll
      for (int kc = 0; kc < 2; ++kc) {
        const int row = wn + nt * 16 + c16;
        b[nt][kc] = *(const bf16x8*)&Bb[(row * 128 + ((((kc * 4 + quad) << 4)) ^ sx)) >> 1];
      }
    __builtin_amdgcn_s_setprio(1);
#pragma unroll
    for (int kc = 0; kc < 2; ++kc)
#pragma unroll
      for (int mt = 0; mt < 4; ++mt)
#pragma unroll
        for (int nt = 0; nt < 4; ++nt)
          acc[mt][nt] = __builtin_amdgcn_mfma_f32_16x16x32_bf16(a[mt][kc], b[nt][kc], acc[mt][nt], 0, 0, 0);
    __builtin_amdgcn_s_setprio(0);
    bc = bc == 2 ? 0 : bc + 1;
  }
#pragma unroll
  for (int mt = 0; mt < 4; ++mt)
#pragma unroll
    for (int nt = 0; nt < 4; ++nt)
#pragma unroll
      for (int r = 0; r < 4; ++r) {
        const int row = bm + wm + mt * 16 + quad * 4 + r;
        const int col = bn + wn + nt * 16 + c16;
        if (MODE == 1)
          ((float*)Cv)[(size_t)row * ldC + col] = acc[mt][nt][r];
        else if (MODE == 0)
          ((u16*)Cv)[(size_t)row * ldC + col] = f2bf(acc[mt][nt][r]);
        else {  // K|V split: cols <1024 -> Kb row-major; >=1024 -> VTb transposed
          if (bn < 1024)
            ((u16*)Cv)[(size_t)row * 1024 + col] = f2bf(acc[mt][nt][r]);
          else
            C2[(size_t)(col - 1024) * 2048 + row] = f2bf(acc[mt][nt][r]);
        }
      }
}

// ---------------------------------------------------------------- gemm3 (occupancy arm)
// BM=128, BN=128, BK=64, 256 thr = 4 waves (2x2, wave owns 64x64).  DOUBLE-
// buffered LDS = 64 KiB -> 2 blocks/CU: while one block sits in the barrier's
// vmcnt drain, the co-resident block streams DMA + MFMA (m114/m97 mechanism;
// m97 sustains 83 GB/s/CU staging at >=3 blocks/CU vs our 31 at 1).  Plain
// __syncthreads per tile (stage-1-ahead into the other buffer); no asm.
// Same pre-swizzled-source layout: lane covers (row = j*32 + w*8 + (l>>3),
// k-slot (l&7)^(l>>3)); row&7 == l>>3 so reads XOR byte ^ ((row&7)<<4).
// MODE: 0 = u16 C, 1 = f32 C.
template <int MODE>
__global__ __launch_bounds__(256, 2) void gemm3(const u16* __restrict__ A,
                                                const u16* __restrict__ Bt,
                                                void* __restrict__ Cv,
                                                int K, int ldC) {
  __shared__ __align__(16) u16 As[2][128 * 64];  // 32 KiB
  __shared__ __align__(16) u16 Bs[2][128 * 64];  // 32 KiB
  const int tid = threadIdx.x, lane = tid & 63, w = tid >> 6;
  const int quad = lane >> 4, c16 = lane & 15;
  const int bm = blockIdx.x * 128, bn = blockIdx.y * 128;
  const int wm = (w >> 1) * 64, wn = (w & 1) * 64;

  const int l3 = lane >> 3, l7 = lane & 7;
  const int ss = l7 ^ l3;
  const u16* Ag = A + (size_t)(bm + w * 8 + l3) * K + ss * 8;
  const u16* Bg = Bt + (size_t)(bn + w * 8 + l3) * K + ss * 8;
  const int sx = (c16 & 7) << 4;  // read-side byte XOR

  f32x4 acc[4][4] = {};
  const int NT = K >> 6;

  // stage(kt): 4 A-loads + 4 B-loads per lane, 32-row j-groups (4 waves x 8)
#define G3_STAGE(buf, k0)                                                   \
  {                                                                         \
    _Pragma("unroll") for (int j = 0; j < 4; ++j)                           \
        load_lds16(Ag + (size_t)j * 32 * K + (k0), As[buf] + j * 2048 + w * 512); \
    _Pragma("unroll") for (int j = 0; j < 4; ++j)                           \
        load_lds16(Bg + (size_t)j * 32 * K + (k0), Bs[buf] + j * 2048 + w * 512); \
  }

  G3_STAGE(0, 0);
  __syncthreads();  // stage(0) landed
  for (int kt = 0; kt < NT; ++kt) {
    const int cur = kt & 1;
    if (kt + 1 < NT) G3_STAGE(cur ^ 1, (kt + 1) << 6);  // overlaps compute below
    const u16* Ab = As[cur];
    const u16* Bb = Bs[cur];
    bf16x8 a[4][2], b[4][2];
#pragma unroll
    for (int mt = 0; mt < 4; ++mt)
#pragma unroll
      for (int kc = 0; kc < 2; ++kc) {
        const int row = wm + mt * 16 + c16;
        a[mt][kc] = *(const bf16x8*)&Ab[(row * 128 + ((((kc * 4 + quad) << 4)) ^ sx)) >> 1];
      }
#pragma unroll
    for (int nt = 0; nt < 4; ++nt)
#pragma unroll
      for (int kc = 0; kc < 2; ++kc) {
        const int row = wn + nt * 16 + c16;
        b[nt][kc] = *(const bf16x8*)&Bb[(row * 128 + ((((kc * 4 + quad) << 4)) ^ sx)) >> 1];
      }
    __builtin_amdgcn_s_setprio(1);
#pragma unroll
    for (int kc = 0; kc < 2; ++kc)
#pragma unroll
      for (int mt = 0; mt < 4; ++mt)
#pragma unroll
        for (int nt = 0; nt < 4; ++nt)
          acc[mt][nt] = __builtin_amdgcn_mfma_f32_16x16x32_bf16(a[mt][kc], b[nt][kc], acc[mt][nt], 0, 0, 0);
    __builtin_amdgcn_s_setprio(0);
    __syncthreads();  // drains stage(kt+1) DMA; certifies buf[cur] reads done
  }
#undef G3_STAGE
#pragma unroll
  for (int mt = 0; mt < 4; ++mt)
#pragma unroll
    for (int nt = 0; nt < 4; ++nt)
#pragma unroll
      for (int r = 0; r < 4; ++r) {
        const int row = bm + wm + mt * 16 + quad * 4 + r;
        const int col = bn + wn + nt * 16 + c16;
        if (MODE == 1)
          ((float*)Cv)[(size_t)row * ldC + col] = acc[mt][nt][r];
        else
          ((u16*)Cv)[(size_t)row * ldC + col] = f2bf(acc[mt][nt][r]);
      }
}

// ---------------------------------------------------------------- RoPE (in place, bf16)
__global__ void rope_kernel(u16* __restrict__ buf, const int* __restrict__ pos,
                            int log2nh, float oscale) {
  const int t = blockIdx.x * 256 + threadIdx.x;
  const int i = t & 63;
  const int h = (t >> 6) & ((1 << log2nh) - 1);
  const int s = t >> (6 + log2nh);
  const int nh = 1 << log2nh;
  const float p = (float)pos[s];
  const float invf = exp2f((float)i * -0.20762051915861040f);  // 10000^(-i/64)
  const float ang = p * invf;
  const float cn = cosf(ang), sn = sinf(ang);
  const size_t i1 = (size_t)s * (nh * 128) + h * 128 + i;
  const size_t i2 = i1 + 64;
  const float x1 = bf2f(buf[i1]), x2 = bf2f(buf[i2]);
  buf[i1] = f2bf((x1 * cn - x2 * sn) * oscale);
  buf[i2] = f2bf((x2 * cn + x1 * sn) * oscale);
}

// ---------------------------------------------------------------- flash attention
// v4 (verified r8/r10): unpaired LPT grid, Q direct-to-reg, K/V reg-prefetch,
// swizzled Ks/Vts, setprio, Ps stride 68.
__global__ __launch_bounds__(256, 2) void flash_kernel(const u16* __restrict__ Q,
                                                       const u16* __restrict__ K,
                                                       const u16* __restrict__ VT,
                                                       u16* __restrict__ O) {
  __shared__ __align__(16) u16 Ks[64 * 128];   // [key][k], swizzled
  __shared__ __align__(16) u16 Vts[128 * 64];  // [d][key], swizzled
  __shared__ __align__(16) u16 Ps[4][16 * 68]; // per-wave P tile, conflict-free
  const int h = blockIdx.x, kvh = h >> 2;
  const int qb = 31 - blockIdx.y;  // LPT: long blocks first
  const int tid = threadIdx.x, lane = tid & 63, w = tid >> 6;
  const int quad = lane >> 4, c16 = lane & 15;
  const int rw = lane >> 2, c4 = lane & 3;
  const int sw = (rw & 7) << 3;
  const int sr = (c16 & 7) << 3;

  bf16x8 aq[4];
#pragma unroll
  for (int kc = 0; kc < 4; ++kc)
    aq[kc] = *(const bf16x8*)&Q[(size_t)(qb * 64 + w * 16 + c16) * 4096 + h * 128 + kc * 32 + quad * 8];

  f32x4 acc_o[8] = {};
  float m_run[4], l_run[4];
#pragma unroll
  for (int r = 0; r < 4; ++r) { m_run[r] = -1e30f; l_run[r] = 0.f; }

  bf16x8 kc_[4], vc_[4];
#pragma unroll
  for (int p = 0; p < 4; ++p) {
    kc_[p] = *(const bf16x8*)&K[(size_t)(w * 16 + rw) * 1024 + kvh * 128 + p * 32 + c4 * 8];
    const int d = (p & 1) * 64 + w * 16 + rw;
    vc_[p] = *(const bf16x8*)&VT[(size_t)(kvh * 128 + d) * 2048 + (p >> 1) * 32 + c4 * 8];
  }

  for (int t = 0; t <= qb; ++t) {
    __syncthreads();
    const int key = w * 16 + rw;
#pragma unroll
    for (int p = 0; p < 4; ++p) {
      *(bf16x8*)&Ks[key * 128 + ((p * 32 + c4 * 8) ^ sw)] = kc_[p];
      const int d = (p & 1) * 64 + w * 16 + rw;
      *(bf16x8*)&Vts[d * 64 + ((((p >> 1) * 32 + c4 * 8)) ^ ((d & 7) << 3))] = vc_[p];
    }
    __syncthreads();
    if (t < qb) {
#pragma unroll
      for (int p = 0; p < 4; ++p) {
        kc_[p] = *(const bf16x8*)&K[(size_t)((t + 1) * 64 + w * 16 + rw) * 1024 + kvh * 128 + p * 32 + c4 * 8];
        const int d = (p & 1) * 64 + w * 16 + rw;
        vc_[p] = *(const bf16x8*)&VT[(size_t)(kvh * 128 + d) * 2048 + (t + 1) * 64 + (p >> 1) * 32 + c4 * 8];
      }
    }

    f32x4 sacc[4];
    __builtin_amdgcn_s_setprio(1);
#pragma unroll
    for (int nt = 0; nt < 4; ++nt) {
      f32x4 s = {0.f, 0.f, 0.f, 0.f};
#pragma unroll
      for (int kc = 0; kc < 4; ++kc) {
        bf16x8 bk = *(const bf16x8*)&Ks[(nt * 16 + c16) * 128 + ((kc * 32 + quad * 8) ^ sr)];
        s = __builtin_amdgcn_mfma_f32_16x16x32_bf16(aq[kc], bk, s, 0, 0, 0);
      }
      sacc[nt] = s;
    }
    __builtin_amdgcn_s_setprio(0);
    if (t == qb) {
#pragma unroll
      for (int nt = 0; nt < 4; ++nt)
#pragma unroll
        for (int r = 0; r < 4; ++r)
          if (nt * 16 + c16 > w * 16 + quad * 4 + r) sacc[nt][r] = -1e30f;
    }
    float al[4];
#pragma unroll
    for (int r = 0; r < 4; ++r) {
      float mx = fmaxf(fmaxf(sacc[0][r], sacc[1][r]), fmaxf(sacc[2][r], sacc[3][r]));
#pragma unroll
      for (int off = 1; off < 16; off <<= 1) mx = fmaxf(mx, __shfl_xor(mx, off));
      const float nm = fmaxf(m_run[r], mx);
      al[r] = __expf(m_run[r] - nm);
      m_run[r] = nm;
      float sum = 0.f;
#pragma unroll
      for (int nt = 0; nt < 4; ++nt) {
        const float pv = __expf(sacc[nt][r] - nm);
        sacc[nt][r] = pv;
        sum += pv;
      }
#pragma unroll
      for (int off = 1; off < 16; off <<= 1) sum += __shfl_xor(sum, off);
      l_run[r] = l_run[r] * al[r] + sum;
    }
#pragma unroll
    for (int dt = 0; dt < 8; ++dt)
#pragma unroll
      for (int r = 0; r < 4; ++r) acc_o[dt][r] *= al[r];
#pragma unroll
    for (int nt = 0; nt < 4; ++nt)
#pragma unroll
      for (int r = 0; r < 4; ++r)
        Ps[w][(quad * 4 + r) * 68 + nt * 16 + c16] = f2bf(sacc[nt][r]);
    asm volatile("s_waitcnt lgkmcnt(0)" ::: "memory");
    bf16x8 ap[2];
#pragma unroll
    for (int kc = 0; kc < 2; ++kc) {
      const u16* pp = &Ps[w][c16 * 68 + kc * 32 + quad * 8];
      bf16x4 lo = *(const bf16x4*)pp;
      bf16x4 hi = *(const bf16x4*)(pp + 4);
      bf16x8 apv;
#pragma unroll
      for (int j = 0; j < 4; ++j) { apv[j] = lo[j]; apv[4 + j] = hi[j]; }
      ap[kc] = apv;
    }
    __builtin_amdgcn_s_setprio(1);
#pragma unroll
    for (int dt = 0; dt < 8; ++dt)
#pragma unroll
      for (int kc = 0; kc < 2; ++kc) {
        bf16x8 bv = *(const bf16x8*)&Vts[(dt * 16 + c16) * 64 + ((kc * 32 + quad * 8) ^ sr)];
        acc_o[dt] = __builtin_amdgcn_mfma_f32_16x16x32_bf16(ap[kc], bv, acc_o[dt], 0, 0, 0);
      }
    __builtin_amdgcn_s_setprio(0);
  }
#pragma unroll
  for (int r = 0; r < 4; ++r) {
    const float inv = 1.0f / l_run[r];
    const int row = qb * 64 + w * 16 + quad * 4 + r;
#pragma unroll
    for (int dt = 0; dt < 8; ++dt)
      O[(size_t)row * 4096 + h * 128 + dt * 16 + c16] = f2bf(acc_o[dt][r] * inv);
  }
}

// ---------------------------------------------------------------- launch
extern "C" void kernel_launch(void* const* d_in, const int* in_sizes, int n_in,
                              void* d_out, int out_size, void* d_ws, size_t ws_size,
                              hipStream_t stream) {
  const float* X  = (const float*)d_in[0];   // [2048,4096] f32
  const int* pos  = (const int*)d_in[2];     // causal mask (d_in[1]) applied analytically
  const float* Wq = (const float*)d_in[3];   // [4096,4096] f32
  const float* Wk = (const float*)d_in[4];   // [4096,1024] f32
  const float* Wv = (const float*)d_in[5];   // [4096,1024] f32
  const float* Wo = (const float*)d_in[6];   // [4096,4096] f32
  float* out = (float*)d_out;                // [2048,4096] f32

  // layouts identical to r10 (verified aliasing audit).
  const int big = ws_size >= (size_t)50331648;
  char* ws = (char*)d_ws;
  u16* WTq  = (u16*)ws;                      // 32 MB, both paths
  u16* WTkv = (u16*)ws;                      // 16 MB, both paths (WTq dead)
  u16* Att, *Xb, *Qb, *Kb, *VTb, *WTo;
  int NPo;
  if (big) {
    Att = (u16*)(ws + 33554432);
    Xb  = Att;                               // dead before flash writes Att
    Qb  = (u16*)d_out;
    Kb  = (u16*)((char*)d_out + 16777216);
    VTb = (u16*)((char*)d_out + 20971520);
    WTo = (u16*)ws;                          // full 32 MB
    NPo = 4096;
  } else {
    Att = (u16*)ws;                          // WTkv dead by flash time
    Xb  = (u16*)d_out;                       // dead after K|V gemm
    Qb  = (u16*)((char*)d_out + 16777216);   // dead after flash
    Kb  = (u16*)(ws + 16777216);             // dead after flash
    VTb = (u16*)(ws + 20971520);
    WTo = (u16*)(ws + 16777216);             // 16 MB panels (Kb/VTb dead)
    NPo = 2048;
  }

  const dim3 b256(256), b512(512);

  // X -> bf16 once (A operand for all projections)
  cvt_bf16_kernel<<<dim3(4096), b256, 0, stream>>>(X, Xb);

  // Q projection: gemm3 occupancy arm — (16,32) = 512 blocks = 2 blocks/CU
  transpose_w<<<dim3(128, 128), b256, 0, stream>>>(Wq, WTq, 4096, 4096, 0);
  gemm3<0><<<dim3(16, 32), b256, 0, stream>>>(Xb, WTq, Qb, 4096, 4096);

  // K|V fused projection (gemm2 control arm)
  transpose_w<<<dim3(32, 128), b256, 0, stream>>>(Wk, WTkv, 4096, 1024, 0);
  transpose_w<<<dim3(32, 128), b256, 0, stream>>>(Wv, WTkv + (size_t)1024 * 4096, 4096, 1024, 0);
  gemm2<2><<<dim3(16, 8), b512, 0, stream>>>(Xb, WTkv, Kb, VTb, 4096, 0);

  // RoPE (Q pre-scaled by 1/sqrt(128))
  rope_kernel<<<dim3(2048 * 32 * 64 / 256), b256, 0, stream>>>(Qb, pos, 5, 0.08838834764831845f);
  rope_kernel<<<dim3(2048 * 8 * 64 / 256),  b256, 0, stream>>>(Kb, pos, 3, 1.0f);

  // unpaired LPT grid: x = head, y: qb = 31 - y -> longest blocks first
  flash_kernel<<<dim3(32, 32), b256, 0, stream>>>(Qb, Kb, VTb, Att);

  // O projection
  if (big) {
    // gemm3 arm at full N: (16,32) = 512 blocks = 2/CU
    transpose_w<<<dim3(128, 128), b256, 0, stream>>>(Wo, WTo, 4096, 4096, 0);
    gemm3<1><<<dim3(16, 32), b256, 0, stream>>>(Att, WTo, out, 4096, 4096);
  } else {
    // gemm2 control arm (2 half-machine panels, as r10)
    for (int p = 0; p < 4096; p += NPo) {
      transpose_w<<<dim3(NPo / 32, 128), b256, 0, stream>>>(Wo, WTo, 4096, 4096, p);
      gemm2<1><<<dim3(16, NPo / 256), b512, 0, stream>>>(Att, WTo, out + p, nullptr, 4096, 4096);
    }
  }
}